// Round 6
// baseline (436.770 us; speedup 1.0000x reference)
//
#include <hip/hip_runtime.h>
#include <hip/hip_bf16.h>

#define TOK 64
#define DIMC 512

typedef __attribute__((ext_vector_type(8))) short v8s;   // 8 bf16 = 4 VGPRs
typedef __attribute__((ext_vector_type(4))) float v4f;   // MFMA 16x16 acc

__device__ __forceinline__ unsigned int f2ord(float f) {
  unsigned int u = __float_as_uint(f);
  return (u & 0x80000000u) ? ~u : (u | 0x80000000u);
}

__device__ __forceinline__ float gelu_exact(float x) {
  return 0.5f * x * (1.0f + erff(x * 0.70710678118654752440f));
}

__device__ __forceinline__ unsigned short f2bf(float x) {  // RNE
  unsigned int u = __float_as_uint(x);
  return (unsigned short)((u + 0x7FFFu + ((u >> 16) & 1u)) >> 16);
}
__device__ __forceinline__ float bf2f(unsigned short h) {
  return __uint_as_float((unsigned int)h << 16);
}

__device__ __forceinline__ void gl2lds16(const void* g, void* l) {
  __builtin_amdgcn_global_load_lds((const __attribute__((address_space(1))) void*)g,
                                   (__attribute__((address_space(3))) void*)l,
                                   16, 0, 0);
}

// ---------------------------------------------------------------------------
// Kernel 1: fused prep. Roles by blockIdx.x:
//   [0,2048)      embed+pool -> hh/hl, init rowmin
//   [2048,2560)   w1 transpose+split
//   [2560,2816)   w2 transpose+split
//   [2816,6912)   codebook split + norms
// ---------------------------------------------------------------------------
__global__ __launch_bounds__(256) void k_prep(
    const int* __restrict__ zt, const int* __restrict__ ztp,
    const float* __restrict__ emb,
    unsigned short* __restrict__ hh, unsigned short* __restrict__ hl,
    unsigned long long* __restrict__ rowmin,
    const float* __restrict__ w1, unsigned short* __restrict__ w1th,
    unsigned short* __restrict__ w1tl,
    const float* __restrict__ w2, unsigned short* __restrict__ w2th,
    unsigned short* __restrict__ w2tl,
    const float* __restrict__ cb, unsigned short* __restrict__ ch,
    unsigned short* __restrict__ cl, float* __restrict__ cnorm) {
  __shared__ int codes[128];
  __shared__ float tbuf[32][33];
  const int bid = blockIdx.x;
  const int tid = threadIdx.x;

  if (bid < 2048) {
    // ---- embed + mean-pool ----
    const int b = bid;
    if (tid < 64) codes[tid] = zt[b * TOK + tid];
    else if (tid < 128) codes[tid] = ztp[b * TOK + (tid - 64)];
    if (tid == 0) rowmin[b] = 0xFFFFFFFFFFFFFFFFull;
    __syncthreads();
    const int half = tid >> 7;
    const int c4 = tid & 127;
    const float4* emb4 = (const float4*)emb;
    float4 s = make_float4(0.f, 0.f, 0.f, 0.f);
    #pragma unroll 8
    for (int t = 0; t < TOK; t++) {
      const int code = codes[half * TOK + t];
      const float4 v = emb4[code * 128 + c4];
      s.x += v.x; s.y += v.y; s.z += v.z; s.w += v.w;
    }
    const float inv = 1.0f / 64.0f;
    float f[4] = {s.x * inv, s.y * inv, s.z * inv, s.w * inv};
    unsigned short hi[4], lo[4];
    #pragma unroll
    for (int i = 0; i < 4; i++) {
      hi[i] = f2bf(f[i]);
      lo[i] = f2bf(f[i] - bf2f(hi[i]));
    }
    const int off = b * 1024 + half * 512 + c4 * 4;
    *(ushort4*)&hh[off] = make_ushort4(hi[0], hi[1], hi[2], hi[3]);
    *(ushort4*)&hl[off] = make_ushort4(lo[0], lo[1], lo[2], lo[3]);
  } else if (bid < 2816) {
    // ---- weight transpose + split ----
    const float* w; unsigned short *wth, *wtl; int Kd, N, k0, n0;
    if (bid < 2560) {
      const int i = bid - 2048;
      w = w1; wth = w1th; wtl = w1tl; Kd = 1024; N = 512;
      k0 = (i & 31) * 32; n0 = (i >> 5) * 32;
    } else {
      const int i = bid - 2560;
      w = w2; wth = w2th; wtl = w2tl; Kd = 512; N = 512;
      k0 = (i & 15) * 32; n0 = (i >> 4) * 32;
    }
    const int c = tid & 31, r = tid >> 5;  // r: 0..7
    #pragma unroll
    for (int i = 0; i < 4; i++)
      tbuf[r + i * 8][c] = w[(size_t)(k0 + r + i * 8) * N + n0 + c];
    __syncthreads();
    #pragma unroll
    for (int i = 0; i < 4; i++) {
      const float v = tbuf[c][r + i * 8];
      const unsigned short hi = f2bf(v);
      const unsigned short lo = f2bf(v - bf2f(hi));
      wth[(size_t)(n0 + r + i * 8) * Kd + k0 + c] = hi;
      wtl[(size_t)(n0 + r + i * 8) * Kd + k0 + c] = lo;
    }
  } else {
    // ---- codebook split + norms (one wave per row) ----
    const int row = (bid - 2816) * 4 + (tid >> 6);
    const int lane = tid & 63;
    const float4* cb4 = (const float4*)cb;
    const float4 va = cb4[row * 128 + lane * 2];
    const float4 vb = cb4[row * 128 + lane * 2 + 1];
    float s = va.x * va.x + va.y * va.y + va.z * va.z + va.w * va.w
            + vb.x * vb.x + vb.y * vb.y + vb.z * vb.z + vb.w * vb.w;
    float f[8] = {va.x, va.y, va.z, va.w, vb.x, vb.y, vb.z, vb.w};
    unsigned short hi[8], lo[8];
    #pragma unroll
    for (int i = 0; i < 8; i++) {
      hi[i] = f2bf(f[i]);
      lo[i] = f2bf(f[i] - bf2f(hi[i]));
    }
    ushort4* chp = (ushort4*)&ch[row * DIMC + lane * 8];
    ushort4* clp = (ushort4*)&cl[row * DIMC + lane * 8];
    chp[0] = make_ushort4(hi[0], hi[1], hi[2], hi[3]);
    chp[1] = make_ushort4(hi[4], hi[5], hi[6], hi[7]);
    clp[0] = make_ushort4(lo[0], lo[1], lo[2], lo[3]);
    clp[1] = make_ushort4(lo[4], lo[5], lo[6], lo[7]);
    #pragma unroll
    for (int off = 32; off > 0; off >>= 1) s += __shfl_down(s, off);
    if (lane == 0) cnorm[row] = s;
  }
}

// ---------------------------------------------------------------------------
// Kernel 2: split-bf16 MFMA GEMM, latency-optimized for small work:
// 32x64 tile (512 blocks = 2/CU), BK=32, DOUBLE-BUFFERED global_load_lds
// (prefetch in flight across the whole compute phase — this kernel is
// latency-bound at low occupancy, unlike the throughput-bound VQ loop).
// ---------------------------------------------------------------------------
template <bool GELU>
__global__ __launch_bounds__(256) void k_gemm(const unsigned short* __restrict__ Ah_,
                                              const unsigned short* __restrict__ Al_,
                                              const unsigned short* __restrict__ Bh_,
                                              const unsigned short* __restrict__ Bl_,
                                              const float* __restrict__ bias,
                                              unsigned short* __restrict__ oh,
                                              unsigned short* __restrict__ ol,
                                              int Kd, int N) {
  __shared__ unsigned short AhS[2][32 * 32];   // 2 KB per buf
  __shared__ unsigned short AlS[2][32 * 32];
  __shared__ unsigned short BhS[2][64 * 32];   // 4 KB per buf
  __shared__ unsigned short BlS[2][64 * 32];

  const int tid = threadIdx.x;
  const int lane = tid & 63;
  const int wid = tid >> 6;
  const int m0 = blockIdx.x * 32;
  const int n0 = blockIdx.y * 64;

  const unsigned short* Ab_h = Ah_ + (size_t)m0 * Kd;
  const unsigned short* Ab_l = Al_ + (size_t)m0 * Kd;
  const unsigned short* Bb_h = Bh_ + (size_t)n0 * Kd;
  const unsigned short* Bb_l = Bl_ + (size_t)n0 * Kd;

  const int srow = lane >> 2;         // 0..15
  const int sk = (lane & 3) * 8;      // shorts
  const int wm = wid >> 1, wn = wid & 1;
  const int fr = lane & 15;
  const int fq = (lane >> 4) * 8;

  v4f acc[2];
  acc[0] = (v4f)(0.f);
  acc[1] = (v4f)(0.f);

  // stage one 32-k slice into buffer `b` (12 issues, 3 per wave)
  auto stage = [&](int b, int k0) {
    #pragma unroll
    for (int u = 0; u < 3; u++) {
      const int i = wid * 3 + u;   // wave-uniform
      const unsigned short* gs; unsigned short* ls; int rbase;
      if (i < 2)      { gs = Ab_h; ls = AhS[b]; rbase = i * 16; }
      else if (i < 4) { gs = Ab_l; ls = AlS[b]; rbase = (i - 2) * 16; }
      else if (i < 8) { gs = Bb_h; ls = BhS[b]; rbase = (i - 4) * 16; }
      else            { gs = Bb_l; ls = BlS[b]; rbase = (i - 8) * 16; }
      gl2lds16(gs + (size_t)(rbase + srow) * Kd + k0 + sk, ls + rbase * 32);
    }
  };

  stage(0, 0);
  int cur = 0;
  for (int k0 = 0; k0 < Kd; k0 += 32) {
    __syncthreads();               // drains vmcnt -> buf `cur` ready
    if (k0 + 32 < Kd) stage(cur ^ 1, k0 + 32);  // in flight during compute

    const int ar = (wm * 16 + fr) * 32 + fq;
    const v8s ah = *(const v8s*)&AhS[cur][ar];
    const v8s al = *(const v8s*)&AlS[cur][ar];
    #pragma unroll
    for (int nt = 0; nt < 2; nt++) {
      const int br = (wn * 32 + nt * 16 + fr) * 32 + fq;
      const v8s bh = *(const v8s*)&BhS[cur][br];
      const v8s bl = *(const v8s*)&BlS[cur][br];
      acc[nt] = __builtin_amdgcn_mfma_f32_16x16x32_bf16(ah, bh, acc[nt], 0, 0, 0);
      acc[nt] = __builtin_amdgcn_mfma_f32_16x16x32_bf16(ah, bl, acc[nt], 0, 0, 0);
      acc[nt] = __builtin_amdgcn_mfma_f32_16x16x32_bf16(al, bh, acc[nt], 0, 0, 0);
    }
    cur ^= 1;
  }

  // epilogue: C/D layout col=lane&15, row=(lane>>4)*4+reg
  const int col16 = lane & 15;
  const int q = lane >> 4;
  #pragma unroll
  for (int nt = 0; nt < 2; nt++) {
    const int col = n0 + wn * 32 + nt * 16 + col16;
    const float bv = bias[col];
    #pragma unroll
    for (int reg = 0; reg < 4; reg++) {
      const int row = m0 + wm * 16 + q * 4 + reg;
      float v = acc[nt][reg] + bv;
      if (GELU) v = gelu_exact(v);
      const unsigned short hi = f2bf(v);
      oh[(size_t)row * N + col] = hi;
      ol[(size_t)row * N + col] = f2bf(v - bf2f(hi));
    }
  }
}

// ---------------------------------------------------------------------------
// Kernel 3: VQ via split-bf16 MFMA GEMM. 128x256 block tile, BK=32,
// 64x128 wave tile. 3 blocks/CU resident (144 KB LDS) to hide barrier
// drains. XCD-swizzled 1-D grid. score = ||c||^2 - 2*e.c
// ---------------------------------------------------------------------------
__global__ __launch_bounds__(256, 3) void k_vq(const unsigned short* __restrict__ eh,
                                               const unsigned short* __restrict__ el,
                                               const unsigned short* __restrict__ ch,
                                               const unsigned short* __restrict__ cl,
                                               const float* __restrict__ cnorm,
                                               unsigned long long* __restrict__ rowmin) {
  __shared__ unsigned short Ah[128 * 32];   //  8 KB
  __shared__ unsigned short Al[128 * 32];   //  8 KB
  __shared__ unsigned short Bh[256 * 32];   // 16 KB
  __shared__ unsigned short Bl[256 * 32];   // 16 KB

  const int tid = threadIdx.x;
  const int lane = tid & 63;
  const int wid = tid >> 6;
  const int bid = blockIdx.x;
  const int j = bid >> 3;
  const int x = j & 15;                      // 16 e-tiles (128 rows)
  const int y = ((j >> 4) << 3) | (bid & 7); // 64 cb-tiles (256 rows)
  const int r0 = x * 128;
  const int c0 = y * 256;

  v4f acc[4][8];
  #pragma unroll
  for (int i = 0; i < 4; i++)
    #pragma unroll
    for (int jj = 0; jj < 8; jj++) acc[i][jj] = (v4f)(0.f);

  const unsigned short* ehB = eh + (size_t)r0 * DIMC;
  const unsigned short* elB = el + (size_t)r0 * DIMC;
  const unsigned short* chB = ch + (size_t)c0 * DIMC;
  const unsigned short* clB = cl + (size_t)c0 * DIMC;

  const int srow = lane >> 2;
  const int sk = (lane & 3) * 8;
  const int wm = wid >> 1;
  const int wn = wid & 1;
  const int fr = lane & 15;
  const int fq = (lane >> 4) * 8;

  for (int k0 = 0; k0 < DIMC; k0 += 32) {
    __syncthreads();
    #pragma unroll
    for (int u = 0; u < 12; u++) {
      const int i = wid * 12 + u;    // wave-uniform
      const unsigned short* gs; unsigned short* ls; int rbase;
      if (i < 8)       { gs = ehB; ls = Ah; rbase = i * 16; }
      else if (i < 16) { gs = elB; ls = Al; rbase = (i - 8) * 16; }
      else if (i < 32) { gs = chB; ls = Bh; rbase = (i - 16) * 16; }
      else             { gs = clB; ls = Bl; rbase = (i - 32) * 16; }
      gl2lds16(gs + (size_t)(rbase + srow) * DIMC + k0 + sk, ls + rbase * 32);
    }
    __syncthreads();

    v8s ahf[4], alf[4];
    #pragma unroll
    for (int mt = 0; mt < 4; mt++) {
      const int ar = (wm * 64 + mt * 16 + fr) * 32 + fq;
      ahf[mt] = *(const v8s*)&Ah[ar];
      alf[mt] = *(const v8s*)&Al[ar];
    }
    #pragma unroll
    for (int nt = 0; nt < 8; nt++) {
      const int br = (wn * 128 + nt * 16 + fr) * 32 + fq;
      const v8s bhf = *(const v8s*)&Bh[br];
      const v8s blf = *(const v8s*)&Bl[br];
      #pragma unroll
      for (int mt = 0; mt < 4; mt++) {
        acc[mt][nt] = __builtin_amdgcn_mfma_f32_16x16x32_bf16(ahf[mt], bhf, acc[mt][nt], 0, 0, 0);
        acc[mt][nt] = __builtin_amdgcn_mfma_f32_16x16x32_bf16(ahf[mt], blf, acc[mt][nt], 0, 0, 0);
        acc[mt][nt] = __builtin_amdgcn_mfma_f32_16x16x32_bf16(alf[mt], bhf, acc[mt][nt], 0, 0, 0);
      }
    }
  }

  // epilogue: C/D layout col=lane&15, row=(lane>>4)*4+reg
  const int col16 = lane & 15;
  const int q = lane >> 4;
  float cn[8];
  #pragma unroll
  for (int nt = 0; nt < 8; nt++) cn[nt] = cnorm[c0 + wn * 128 + nt * 16 + col16];

  #pragma unroll
  for (int mt = 0; mt < 4; mt++) {
    #pragma unroll
    for (int reg = 0; reg < 4; reg++) {
      const int row = r0 + wm * 64 + mt * 16 + q * 4 + reg;
      float best = fmaf(-2.f, acc[mt][0][reg], cn[0]);
      int bid2 = c0 + wn * 128 + col16;
      #pragma unroll
      for (int nt = 1; nt < 8; nt++) {
        const float s = fmaf(-2.f, acc[mt][nt][reg], cn[nt]);
        const int id = c0 + wn * 128 + nt * 16 + col16;
        if (s < best) { best = s; bid2 = id; }
      }
      unsigned long long v =
          ((unsigned long long)f2ord(best) << 32) | (unsigned int)bid2;
      #pragma unroll
      for (int off = 8; off > 0; off >>= 1) {
        const unsigned long long o = __shfl_down(v, off, 16);
        if (o < v) v = o;
      }
      if (col16 == 0) atomicMin(&rowmin[row], v);
    }
  }
}

// ---------------------------------------------------------------------------
// Kernel 4: finalize — ids as float + gather q rows.
// ---------------------------------------------------------------------------
__global__ __launch_bounds__(64) void k_final(const unsigned long long* __restrict__ rowmin,
                                              const float* __restrict__ cb,
                                              float* __restrict__ out,
                                              int B) {
  const int b = blockIdx.x;
  const int t = threadIdx.x;
  const unsigned long long m = rowmin[b];
  const int id = (int)(unsigned int)(m & 0xFFFFFFFFull);
  if (t == 0) out[b] = (float)id;
  float4* q4 = (float4*)(out + B) + b * 128;
  const float4* cb4 = (const float4*)cb + (size_t)id * 128;
  q4[t] = cb4[t];
  q4[t + 64] = cb4[t + 64];
}

// ---------------------------------------------------------------------------
extern "C" void kernel_launch(void* const* d_in, const int* in_sizes, int n_in,
                              void* d_out, int out_size, void* d_ws, size_t ws_size,
                              hipStream_t stream) {
  const int* zt = (const int*)d_in[0];
  const int* ztp = (const int*)d_in[1];
  const float* emb = (const float*)d_in[2];
  const float* w1 = (const float*)d_in[3];
  const float* b1 = (const float*)d_in[4];
  const float* w2 = (const float*)d_in[5];
  const float* b2 = (const float*)d_in[6];
  const float* cb = (const float*)d_in[7];
  float* out = (float*)d_out;

  const int B = in_sizes[0] / TOK;        // 2048
  const int A = in_sizes[7] / DIMC;       // 16384

  char* p = (char*)d_ws;
  unsigned short* hh = (unsigned short*)p;  p += (size_t)B * 1024 * 2;
  unsigned short* hl = (unsigned short*)p;  p += (size_t)B * 1024 * 2;
  unsigned short* w1th = (unsigned short*)p; p += (size_t)512 * 1024 * 2;
  unsigned short* w1tl = (unsigned short*)p; p += (size_t)512 * 1024 * 2;
  unsigned short* w2th = (unsigned short*)p; p += (size_t)512 * 512 * 2;
  unsigned short* w2tl = (unsigned short*)p; p += (size_t)512 * 512 * 2;
  unsigned short* h1h = (unsigned short*)p; p += (size_t)B * DIMC * 2;
  unsigned short* h1l = (unsigned short*)p; p += (size_t)B * DIMC * 2;
  unsigned short* eh = (unsigned short*)p;  p += (size_t)B * DIMC * 2;
  unsigned short* el = (unsigned short*)p;  p += (size_t)B * DIMC * 2;
  unsigned short* ch = (unsigned short*)p;  p += (size_t)A * DIMC * 2;
  unsigned short* cl = (unsigned short*)p;  p += (size_t)A * DIMC * 2;
  float* cnorm = (float*)p;                 p += (size_t)A * 4;
  unsigned long long* rowmin = (unsigned long long*)p;

  k_prep<<<2816 + A / 4, 256, 0, stream>>>(zt, ztp, emb, hh, hl, rowmin,
                                           w1, w1th, w1tl, w2, w2th, w2tl,
                                           cb, ch, cl, cnorm);
  k_gemm<true><<<dim3(B / 32, 512 / 64), 256, 0, stream>>>(hh, hl, w1th, w1tl, b1, h1h, h1l, 1024, 512);
  k_gemm<false><<<dim3(B / 32, 512 / 64), 256, 0, stream>>>(h1h, h1l, w2th, w2tl, b2, eh, el, 512, 512);
  k_vq<<<(B / 128) * (A / 256), 256, 0, stream>>>(eh, el, ch, cl, cnorm, rowmin);
  k_final<<<B, 64, 0, stream>>>(rowmin, cb, out, B);
}

// Round 7
// 234.597 us; speedup vs baseline: 1.8618x; 1.8618x over previous
//
#include <hip/hip_runtime.h>
#include <hip/hip_bf16.h>

#define TOK 64
#define DIMC 512

typedef __attribute__((ext_vector_type(8))) short v8s;   // 8 bf16 = 4 VGPRs
typedef __attribute__((ext_vector_type(4))) float v4f;   // MFMA 16x16 acc

__device__ __forceinline__ unsigned int f2ord(float f) {
  unsigned int u = __float_as_uint(f);
  return (u & 0x80000000u) ? ~u : (u | 0x80000000u);
}

__device__ __forceinline__ float gelu_exact(float x) {
  return 0.5f * x * (1.0f + erff(x * 0.70710678118654752440f));
}

__device__ __forceinline__ unsigned short f2bf(float x) {  // RNE
  unsigned int u = __float_as_uint(x);
  return (unsigned short)((u + 0x7FFFu + ((u >> 16) & 1u)) >> 16);
}
__device__ __forceinline__ float bf2f(unsigned short h) {
  return __uint_as_float((unsigned int)h << 16);
}

__device__ __forceinline__ void gl2lds16(const void* g, void* l) {
  __builtin_amdgcn_global_load_lds((const __attribute__((address_space(1))) void*)g,
                                   (__attribute__((address_space(3))) void*)l,
                                   16, 0, 0);
}

// ---------------------------------------------------------------------------
// Kernel 1: fused prep. Roles by blockIdx.x:
//   [0,2048)      embed+pool -> hh/hl, init rowmin
//   [2048,2560)   w1 transpose+split
//   [2560,2816)   w2 transpose+split
//   [2816,6912)   codebook split + norms
// ---------------------------------------------------------------------------
__global__ __launch_bounds__(256) void k_prep(
    const int* __restrict__ zt, const int* __restrict__ ztp,
    const float* __restrict__ emb,
    unsigned short* __restrict__ hh, unsigned short* __restrict__ hl,
    unsigned long long* __restrict__ rowmin,
    const float* __restrict__ w1, unsigned short* __restrict__ w1th,
    unsigned short* __restrict__ w1tl,
    const float* __restrict__ w2, unsigned short* __restrict__ w2th,
    unsigned short* __restrict__ w2tl,
    const float* __restrict__ cb, unsigned short* __restrict__ ch,
    unsigned short* __restrict__ cl, float* __restrict__ cnorm) {
  __shared__ int codes[128];
  __shared__ float tbuf[32][33];
  const int bid = blockIdx.x;
  const int tid = threadIdx.x;

  if (bid < 2048) {
    // ---- embed + mean-pool ----
    const int b = bid;
    if (tid < 64) codes[tid] = zt[b * TOK + tid];
    else if (tid < 128) codes[tid] = ztp[b * TOK + (tid - 64)];
    if (tid == 0) rowmin[b] = 0xFFFFFFFFFFFFFFFFull;
    __syncthreads();
    const int half = tid >> 7;
    const int c4 = tid & 127;
    const float4* emb4 = (const float4*)emb;
    float4 s = make_float4(0.f, 0.f, 0.f, 0.f);
    #pragma unroll 8
    for (int t = 0; t < TOK; t++) {
      const int code = codes[half * TOK + t];
      const float4 v = emb4[code * 128 + c4];
      s.x += v.x; s.y += v.y; s.z += v.z; s.w += v.w;
    }
    const float inv = 1.0f / 64.0f;
    float f[4] = {s.x * inv, s.y * inv, s.z * inv, s.w * inv};
    unsigned short hi[4], lo[4];
    #pragma unroll
    for (int i = 0; i < 4; i++) {
      hi[i] = f2bf(f[i]);
      lo[i] = f2bf(f[i] - bf2f(hi[i]));
    }
    const int off = b * 1024 + half * 512 + c4 * 4;
    *(ushort4*)&hh[off] = make_ushort4(hi[0], hi[1], hi[2], hi[3]);
    *(ushort4*)&hl[off] = make_ushort4(lo[0], lo[1], lo[2], lo[3]);
  } else if (bid < 2816) {
    // ---- weight transpose + split ----
    const float* w; unsigned short *wth, *wtl; int Kd, N, k0, n0;
    if (bid < 2560) {
      const int i = bid - 2048;
      w = w1; wth = w1th; wtl = w1tl; Kd = 1024; N = 512;
      k0 = (i & 31) * 32; n0 = (i >> 5) * 32;
    } else {
      const int i = bid - 2560;
      w = w2; wth = w2th; wtl = w2tl; Kd = 512; N = 512;
      k0 = (i & 15) * 32; n0 = (i >> 4) * 32;
    }
    const int c = tid & 31, r = tid >> 5;  // r: 0..7
    #pragma unroll
    for (int i = 0; i < 4; i++)
      tbuf[r + i * 8][c] = w[(size_t)(k0 + r + i * 8) * N + n0 + c];
    __syncthreads();
    #pragma unroll
    for (int i = 0; i < 4; i++) {
      const float v = tbuf[c][r + i * 8];
      const unsigned short hi = f2bf(v);
      const unsigned short lo = f2bf(v - bf2f(hi));
      wth[(size_t)(n0 + r + i * 8) * Kd + k0 + c] = hi;
      wtl[(size_t)(n0 + r + i * 8) * Kd + k0 + c] = lo;
    }
  } else {
    // ---- codebook split + norms (one wave per row) ----
    const int row = (bid - 2816) * 4 + (tid >> 6);
    const int lane = tid & 63;
    const float4* cb4 = (const float4*)cb;
    const float4 va = cb4[row * 128 + lane * 2];
    const float4 vb = cb4[row * 128 + lane * 2 + 1];
    float s = va.x * va.x + va.y * va.y + va.z * va.z + va.w * va.w
            + vb.x * vb.x + vb.y * vb.y + vb.z * vb.z + vb.w * vb.w;
    float f[8] = {va.x, va.y, va.z, va.w, vb.x, vb.y, vb.z, vb.w};
    unsigned short hi[8], lo[8];
    #pragma unroll
    for (int i = 0; i < 8; i++) {
      hi[i] = f2bf(f[i]);
      lo[i] = f2bf(f[i] - bf2f(hi[i]));
    }
    ushort4* chp = (ushort4*)&ch[row * DIMC + lane * 8];
    ushort4* clp = (ushort4*)&cl[row * DIMC + lane * 8];
    chp[0] = make_ushort4(hi[0], hi[1], hi[2], hi[3]);
    chp[1] = make_ushort4(hi[4], hi[5], hi[6], hi[7]);
    clp[0] = make_ushort4(lo[0], lo[1], lo[2], lo[3]);
    clp[1] = make_ushort4(lo[4], lo[5], lo[6], lo[7]);
    #pragma unroll
    for (int off = 32; off > 0; off >>= 1) s += __shfl_down(s, off);
    if (lane == 0) cnorm[row] = s;
  }
}

// ---------------------------------------------------------------------------
// Kernel 2: split-bf16 MFMA GEMM, latency-optimized for small work:
// 32x64 tile (512 blocks = 2/CU), BK=32, DOUBLE-BUFFERED global_load_lds.
// ---------------------------------------------------------------------------
template <bool GELU>
__global__ __launch_bounds__(256) void k_gemm(const unsigned short* __restrict__ Ah_,
                                              const unsigned short* __restrict__ Al_,
                                              const unsigned short* __restrict__ Bh_,
                                              const unsigned short* __restrict__ Bl_,
                                              const float* __restrict__ bias,
                                              unsigned short* __restrict__ oh,
                                              unsigned short* __restrict__ ol,
                                              int Kd, int N) {
  __shared__ unsigned short AhS[2][32 * 32];   // 2 KB per buf
  __shared__ unsigned short AlS[2][32 * 32];
  __shared__ unsigned short BhS[2][64 * 32];   // 4 KB per buf
  __shared__ unsigned short BlS[2][64 * 32];

  const int tid = threadIdx.x;
  const int lane = tid & 63;
  const int wid = tid >> 6;
  const int m0 = blockIdx.x * 32;
  const int n0 = blockIdx.y * 64;

  const unsigned short* Ab_h = Ah_ + (size_t)m0 * Kd;
  const unsigned short* Ab_l = Al_ + (size_t)m0 * Kd;
  const unsigned short* Bb_h = Bh_ + (size_t)n0 * Kd;
  const unsigned short* Bb_l = Bl_ + (size_t)n0 * Kd;

  const int srow = lane >> 2;         // 0..15
  const int sk = (lane & 3) * 8;      // shorts
  const int wm = wid >> 1, wn = wid & 1;
  const int fr = lane & 15;
  const int fq = (lane >> 4) * 8;

  v4f acc[2];
  acc[0] = (v4f)(0.f);
  acc[1] = (v4f)(0.f);

  // stage one 32-k slice into buffer `b` (12 issues, 3 per wave)
  auto stage = [&](int b, int k0) {
    #pragma unroll
    for (int u = 0; u < 3; u++) {
      const int i = wid * 3 + u;   // wave-uniform
      const unsigned short* gs; unsigned short* ls; int rbase;
      if (i < 2)      { gs = Ab_h; ls = AhS[b]; rbase = i * 16; }
      else if (i < 4) { gs = Ab_l; ls = AlS[b]; rbase = (i - 2) * 16; }
      else if (i < 8) { gs = Bb_h; ls = BhS[b]; rbase = (i - 4) * 16; }
      else            { gs = Bb_l; ls = BlS[b]; rbase = (i - 8) * 16; }
      gl2lds16(gs + (size_t)(rbase + srow) * Kd + k0 + sk, ls + rbase * 32);
    }
  };

  stage(0, 0);
  int cur = 0;
  for (int k0 = 0; k0 < Kd; k0 += 32) {
    __syncthreads();               // drains vmcnt -> buf `cur` ready
    if (k0 + 32 < Kd) stage(cur ^ 1, k0 + 32);  // in flight during compute

    const int ar = (wm * 16 + fr) * 32 + fq;
    const v8s ah = *(const v8s*)&AhS[cur][ar];
    const v8s al = *(const v8s*)&AlS[cur][ar];
    #pragma unroll
    for (int nt = 0; nt < 2; nt++) {
      const int br = (wn * 32 + nt * 16 + fr) * 32 + fq;
      const v8s bh = *(const v8s*)&BhS[cur][br];
      const v8s bl = *(const v8s*)&BlS[cur][br];
      acc[nt] = __builtin_amdgcn_mfma_f32_16x16x32_bf16(ah, bh, acc[nt], 0, 0, 0);
      acc[nt] = __builtin_amdgcn_mfma_f32_16x16x32_bf16(ah, bl, acc[nt], 0, 0, 0);
      acc[nt] = __builtin_amdgcn_mfma_f32_16x16x32_bf16(al, bh, acc[nt], 0, 0, 0);
    }
    cur ^= 1;
  }

  // epilogue: C/D layout col=lane&15, row=(lane>>4)*4+reg
  const int col16 = lane & 15;
  const int q = lane >> 4;
  #pragma unroll
  for (int nt = 0; nt < 2; nt++) {
    const int col = n0 + wn * 32 + nt * 16 + col16;
    const float bv = bias[col];
    #pragma unroll
    for (int reg = 0; reg < 4; reg++) {
      const int row = m0 + wm * 16 + q * 4 + reg;
      float v = acc[nt][reg] + bv;
      if (GELU) v = gelu_exact(v);
      const unsigned short hi = f2bf(v);
      oh[(size_t)row * N + col] = hi;
      ol[(size_t)row * N + col] = f2bf(v - bf2f(hi));
    }
  }
}

// ---------------------------------------------------------------------------
// Kernel 3: VQ via split-bf16 MFMA GEMM. 128x256 block tile, BK=32,
// 64x128 wave tile. __launch_bounds__(256,2): (256,3) caps regs at ~170/wave
// and SPILLS the 128-reg accumulator (round 6: WRITE_SIZE 8->584 MB, 3.6x
// regression). Registers, not LDS, bound occupancy here.
// XCD-swizzled 1-D grid. score = ||c||^2 - 2*e.c
// ---------------------------------------------------------------------------
__global__ __launch_bounds__(256, 2) void k_vq(const unsigned short* __restrict__ eh,
                                               const unsigned short* __restrict__ el,
                                               const unsigned short* __restrict__ ch,
                                               const unsigned short* __restrict__ cl,
                                               const float* __restrict__ cnorm,
                                               unsigned long long* __restrict__ rowmin) {
  __shared__ unsigned short Ah[128 * 32];   //  8 KB
  __shared__ unsigned short Al[128 * 32];   //  8 KB
  __shared__ unsigned short Bh[256 * 32];   // 16 KB
  __shared__ unsigned short Bl[256 * 32];   // 16 KB

  const int tid = threadIdx.x;
  const int lane = tid & 63;
  const int wid = tid >> 6;
  const int bid = blockIdx.x;
  const int j = bid >> 3;
  const int x = j & 15;                      // 16 e-tiles (128 rows)
  const int y = ((j >> 4) << 3) | (bid & 7); // 64 cb-tiles (256 rows)
  const int r0 = x * 128;
  const int c0 = y * 256;

  v4f acc[4][8];
  #pragma unroll
  for (int i = 0; i < 4; i++)
    #pragma unroll
    for (int jj = 0; jj < 8; jj++) acc[i][jj] = (v4f)(0.f);

  const unsigned short* ehB = eh + (size_t)r0 * DIMC;
  const unsigned short* elB = el + (size_t)r0 * DIMC;
  const unsigned short* chB = ch + (size_t)c0 * DIMC;
  const unsigned short* clB = cl + (size_t)c0 * DIMC;

  const int srow = lane >> 2;
  const int sk = (lane & 3) * 8;
  const int wm = wid >> 1;
  const int wn = wid & 1;
  const int fr = lane & 15;
  const int fq = (lane >> 4) * 8;

  for (int k0 = 0; k0 < DIMC; k0 += 32) {
    __syncthreads();
    #pragma unroll
    for (int u = 0; u < 12; u++) {
      const int i = wid * 12 + u;    // wave-uniform
      const unsigned short* gs; unsigned short* ls; int rbase;
      if (i < 8)       { gs = ehB; ls = Ah; rbase = i * 16; }
      else if (i < 16) { gs = elB; ls = Al; rbase = (i - 8) * 16; }
      else if (i < 32) { gs = chB; ls = Bh; rbase = (i - 16) * 16; }
      else             { gs = clB; ls = Bl; rbase = (i - 32) * 16; }
      gl2lds16(gs + (size_t)(rbase + srow) * DIMC + k0 + sk, ls + rbase * 32);
    }
    __syncthreads();

    v8s ahf[4], alf[4];
    #pragma unroll
    for (int mt = 0; mt < 4; mt++) {
      const int ar = (wm * 64 + mt * 16 + fr) * 32 + fq;
      ahf[mt] = *(const v8s*)&Ah[ar];
      alf[mt] = *(const v8s*)&Al[ar];
    }
    #pragma unroll
    for (int nt = 0; nt < 8; nt++) {
      const int br = (wn * 128 + nt * 16 + fr) * 32 + fq;
      const v8s bhf = *(const v8s*)&Bh[br];
      const v8s blf = *(const v8s*)&Bl[br];
      #pragma unroll
      for (int mt = 0; mt < 4; mt++) {
        acc[mt][nt] = __builtin_amdgcn_mfma_f32_16x16x32_bf16(ahf[mt], bhf, acc[mt][nt], 0, 0, 0);
        acc[mt][nt] = __builtin_amdgcn_mfma_f32_16x16x32_bf16(ahf[mt], blf, acc[mt][nt], 0, 0, 0);
        acc[mt][nt] = __builtin_amdgcn_mfma_f32_16x16x32_bf16(alf[mt], bhf, acc[mt][nt], 0, 0, 0);
      }
    }
  }

  // epilogue: C/D layout col=lane&15, row=(lane>>4)*4+reg
  const int col16 = lane & 15;
  const int q = lane >> 4;
  float cn[8];
  #pragma unroll
  for (int nt = 0; nt < 8; nt++) cn[nt] = cnorm[c0 + wn * 128 + nt * 16 + col16];

  #pragma unroll
  for (int mt = 0; mt < 4; mt++) {
    #pragma unroll
    for (int reg = 0; reg < 4; reg++) {
      const int row = r0 + wm * 64 + mt * 16 + q * 4 + reg;
      float best = fmaf(-2.f, acc[mt][0][reg], cn[0]);
      int bid2 = c0 + wn * 128 + col16;
      #pragma unroll
      for (int nt = 1; nt < 8; nt++) {
        const float s = fmaf(-2.f, acc[mt][nt][reg], cn[nt]);
        const int id = c0 + wn * 128 + nt * 16 + col16;
        if (s < best) { best = s; bid2 = id; }
      }
      unsigned long long v =
          ((unsigned long long)f2ord(best) << 32) | (unsigned int)bid2;
      #pragma unroll
      for (int off = 8; off > 0; off >>= 1) {
        const unsigned long long o = __shfl_down(v, off, 16);
        if (o < v) v = o;
      }
      if (col16 == 0) atomicMin(&rowmin[row], v);
    }
  }
}

// ---------------------------------------------------------------------------
// Kernel 4: finalize — ids as float + gather q rows.
// ---------------------------------------------------------------------------
__global__ __launch_bounds__(64) void k_final(const unsigned long long* __restrict__ rowmin,
                                              const float* __restrict__ cb,
                                              float* __restrict__ out,
                                              int B) {
  const int b = blockIdx.x;
  const int t = threadIdx.x;
  const unsigned long long m = rowmin[b];
  const int id = (int)(unsigned int)(m & 0xFFFFFFFFull);
  if (t == 0) out[b] = (float)id;
  float4* q4 = (float4*)(out + B) + b * 128;
  const float4* cb4 = (const float4*)cb + (size_t)id * 128;
  q4[t] = cb4[t];
  q4[t + 64] = cb4[t + 64];
}

// ---------------------------------------------------------------------------
extern "C" void kernel_launch(void* const* d_in, const int* in_sizes, int n_in,
                              void* d_out, int out_size, void* d_ws, size_t ws_size,
                              hipStream_t stream) {
  const int* zt = (const int*)d_in[0];
  const int* ztp = (const int*)d_in[1];
  const float* emb = (const float*)d_in[2];
  const float* w1 = (const float*)d_in[3];
  const float* b1 = (const float*)d_in[4];
  const float* w2 = (const float*)d_in[5];
  const float* b2 = (const float*)d_in[6];
  const float* cb = (const float*)d_in[7];
  float* out = (float*)d_out;

  const int B = in_sizes[0] / TOK;        // 2048
  const int A = in_sizes[7] / DIMC;       // 16384

  char* p = (char*)d_ws;
  unsigned short* hh = (unsigned short*)p;  p += (size_t)B * 1024 * 2;
  unsigned short* hl = (unsigned short*)p;  p += (size_t)B * 1024 * 2;
  unsigned short* w1th = (unsigned short*)p; p += (size_t)512 * 1024 * 2;
  unsigned short* w1tl = (unsigned short*)p; p += (size_t)512 * 1024 * 2;
  unsigned short* w2th = (unsigned short*)p; p += (size_t)512 * 512 * 2;
  unsigned short* w2tl = (unsigned short*)p; p += (size_t)512 * 512 * 2;
  unsigned short* h1h = (unsigned short*)p; p += (size_t)B * DIMC * 2;
  unsigned short* h1l = (unsigned short*)p; p += (size_t)B * DIMC * 2;
  unsigned short* eh = (unsigned short*)p;  p += (size_t)B * DIMC * 2;
  unsigned short* el = (unsigned short*)p;  p += (size_t)B * DIMC * 2;
  unsigned short* ch = (unsigned short*)p;  p += (size_t)A * DIMC * 2;
  unsigned short* cl = (unsigned short*)p;  p += (size_t)A * DIMC * 2;
  float* cnorm = (float*)p;                 p += (size_t)A * 4;
  unsigned long long* rowmin = (unsigned long long*)p;

  k_prep<<<2816 + A / 4, 256, 0, stream>>>(zt, ztp, emb, hh, hl, rowmin,
                                           w1, w1th, w1tl, w2, w2th, w2tl,
                                           cb, ch, cl, cnorm);
  k_gemm<true><<<dim3(B / 32, 512 / 64), 256, 0, stream>>>(hh, hl, w1th, w1tl, b1, h1h, h1l, 1024, 512);
  k_gemm<false><<<dim3(B / 32, 512 / 64), 256, 0, stream>>>(h1h, h1l, w2th, w2tl, b2, eh, el, 512, 512);
  k_vq<<<(B / 128) * (A / 256), 256, 0, stream>>>(eh, el, ch, cl, cnorm, rowmin);
  k_final<<<B, 64, 0, stream>>>(rowmin, cb, out, B);
}